// Round 1
// baseline (459.432 us; speedup 1.0000x reference)
//
#include <hip/hip_runtime.h>
#include <hip/hip_bf16.h>

#define BN 16384
#define TT 12
#define MLP 1024
#define ZD 32
#define HD 128
#define KD 1056          // MLP+ZD
#define GN 384           // 3*H
#define WIH_LD 1060      // MLP+ZD+2*NPRED
#define NSG 4
#define DTC 1.6f
#define PLD 512          // P leading dim: [gates_zx(384) | h0(128)]
#define SLD 40           // GEMM LDS tile row stride (bf16): 80B -> <=2-way banks
#define GRU_ROWS 16      // rows per k_gru block (256 threads, 4 waves)

typedef __attribute__((ext_vector_type(8))) short short8;
typedef __attribute__((ext_vector_type(4))) short short4_t;
typedef __attribute__((ext_vector_type(4))) float floatx4;
typedef __hip_bfloat16 bf16;

__device__ __forceinline__ float bf2f(bf16 v) { return __bfloat162float(v); }
__device__ __forceinline__ bf16 f2bf(float v) { return __float2bfloat16(v); }
__device__ __forceinline__ short bfbits(float x) {
    bf16 t = __float2bfloat16(x);
    return __builtin_bit_cast(short, t);
}
__device__ __forceinline__ float bfraw2f(unsigned short u) {
    return __uint_as_float(((unsigned int)u) << 16);
}
// rcp-based gates: saves div sequence; |err| ~1ulp of rcp, fine vs 3.4e-2 thr
__device__ __forceinline__ float sigm(float x) {
    return __builtin_amdgcn_rcpf(1.0f + __expf(-x));
}
__device__ __forceinline__ float tanh_f(float x) {
    return 1.0f - 2.0f * __builtin_amdgcn_rcpf(1.0f + __expf(2.0f * x));
}
__device__ __forceinline__ short8 pack8(floatx4 a, floatx4 b) {
    short8 v;
    v[0]=bfbits(a[0]); v[1]=bfbits(a[1]); v[2]=bfbits(a[2]); v[3]=bfbits(a[3]);
    v[4]=bfbits(b[0]); v[5]=bfbits(b[1]); v[6]=bfbits(b[2]); v[7]=bfbits(b[3]);
    return v;
}
__device__ __forceinline__ short8 ld8f(const float* q) {
    return pack8(*(const floatx4*)q, *(const floatx4*)(q + 4));
}
// barrier that waits LDS ops only — leaves global loads/stores in flight
__device__ __forceinline__ void barrier_lgkm() {
    asm volatile("s_waitcnt lgkmcnt(0)\n\ts_barrier" ::: "memory");
}

struct GP {
    const float *lst, *lpos, *enc, *zz, *sg, *fut;
    const int* upd;
    const float *Wdec, *bdec, *Wtv, *btv, *Wih, *bih, *Whh, *bhh;
    const float *Wmu, *bmu, *Wstd, *bstd, *Wsg, *bsg;
    const bf16* P;        // null in fused path
    float* out;
};

// ---------------------------------------------------------------------------
// k_gemm: P[B,512] = zx @ [W_ih[:, :1056] | W_dec_hidden]^T  (raw, no bias)
// Tile 128x128, grid (128,4). Double-buffered LDS, 2-deep register prefetch,
// one lgkm-only barrier per kc (global loads fly across barriers).
// (unchanged this round — k_gru is the measured bottleneck)
// ---------------------------------------------------------------------------
__global__ __launch_bounds__(512, 4) void k_gemm(
    const float* __restrict__ enc, const float* __restrict__ zz,
    const float* __restrict__ Wih, const float* __restrict__ Wdec,
    bf16* __restrict__ P)
{
    __shared__ __align__(16) bf16 sA[2][128 * SLD];
    __shared__ __align__(16) bf16 sB[2][128 * SLD];
    const int tid = threadIdx.x;
    const int lane = tid & 63;
    const int wav = tid >> 6;
    const int wm2 = wav >> 2;         // 0..1
    const int wn2 = wav & 3;          // 0..3
    const int c = lane & 15;
    const int quad = lane >> 4;
    const int m0 = blockIdx.x * 128;
    const int n0 = blockIdx.y * 128;

    const int srow = tid >> 2;        // 0..127
    const int scq = (tid & 3) * 8;    // 0/8/16/24
    const int nn = n0 + srow;
    const float* arow = enc + (size_t)(m0 + srow) * MLP + scq;
    const float* zrow = zz + (size_t)(m0 + srow) * ZD + scq;
    const float* brow = (nn < GN) ? Wih + (size_t)nn * WIH_LD + scq
                                  : Wdec + (size_t)(nn - GN) * KD + scq;

    floatx4 pa[2][2], pb[2][2];
    // preload kc=0 (slot 0) and kc=1 (slot 1)
#pragma unroll
    for (int s0 = 0; s0 < 2; s0++) {
        const float* qa = arow + s0 * 32;
        const float* qb = brow + s0 * 32;
        pa[s0][0] = *(const floatx4*)qa; pa[s0][1] = *(const floatx4*)(qa + 4);
        pb[s0][0] = *(const floatx4*)qb; pb[s0][1] = *(const floatx4*)(qb + 4);
    }

    floatx4 acc[4][2];
#pragma unroll
    for (int i = 0; i < 4; i++)
#pragma unroll
        for (int j = 0; j < 2; j++) acc[i][j] = floatx4{0.f, 0.f, 0.f, 0.f};

    for (int kc = 0; kc < 33; kc++) {
        const int sl = kc & 1;
        *(short8*)&sA[sl][srow * SLD + scq] = pack8(pa[sl][0], pa[sl][1]);
        *(short8*)&sB[sl][srow * SLD + scq] = pack8(pb[sl][0], pb[sl][1]);
        if (kc + 2 < 33) {
            const int k2 = (kc + 2) * 32;
            const float* qa = (kc + 2 < 32) ? arow + k2 : zrow;
            const float* qb = brow + k2;
            pa[sl][0] = *(const floatx4*)qa; pa[sl][1] = *(const floatx4*)(qa + 4);
            pb[sl][0] = *(const floatx4*)qb; pb[sl][1] = *(const floatx4*)(qb + 4);
        }
        barrier_lgkm();
        short8 a[4], b[2];
#pragma unroll
        for (int i = 0; i < 4; i++)
            a[i] = *(const short8*)&sA[sl][(wm2 * 64 + i * 16 + c) * SLD + quad * 8];
#pragma unroll
        for (int j = 0; j < 2; j++)
            b[j] = *(const short8*)&sB[sl][(wn2 * 32 + j * 16 + c) * SLD + quad * 8];
#pragma unroll
        for (int i = 0; i < 4; i++)
#pragma unroll
            for (int j = 0; j < 2; j++)
                acc[i][j] = __builtin_amdgcn_mfma_f32_16x16x32_bf16(
                    a[i], b[j], acc[i][j], 0, 0, 0);
        // no trailing barrier: next iter writes the other LDS slot; all waves'
        // slot-sl reads are lgkm-complete before anyone passes the next barrier
    }
#pragma unroll
    for (int i = 0; i < 4; i++)
#pragma unroll
        for (int j = 0; j < 2; j++)
#pragma unroll
            for (int r = 0; r < 4; r++)
                P[(size_t)(m0 + wm2 * 64 + i * 16 + quad * 4 + r) * PLD
                  + n0 + wn2 * 32 + j * 16 + c] = f2bf(acc[i][j][r]);
}

// ---------------------------------------------------------------------------
// GRU kernel. FUSED=1: in-block pre-GEMM (ws too small). FUSED=0: read P.
// NEW this round: 256 threads / 16 rows / 1024 blocks (was 512/32/512).
// Same per-wave register layout (each wave owns 32 gate-cols x 3 gates), same
// 16 waves/CU, but 4 independent barrier domains per CU instead of 2 and
// barrier scope halved 8->4 waves — attacks the measured barrier convoy
// (Occupancy 20.5%, VALUBusy 29%, nothing saturated). Also removes the
// wm-duplicate Whh fragment loads.
// ---------------------------------------------------------------------------
template<int FUSED> struct SMem {
    static constexpr int PRE_N = FUSED ? GRU_ROWS * 512 : 16;
    bf16 pre[PRE_N];
    bf16 h[2][GRU_ROWS][136];   // 272B rows: 2-way banks (free) for b128 reads
    bf16 ext[TT][GRU_ROWS][4];  // per-step (a0,a1,sg0,sg1)
    float sgf[NSG][GRU_ROWS][2];
    float a0[GRU_ROWS][2];
    float muw[4][132];          // +4 pad: kills 4-way same-bank head reads
    float b4[4];
};

template<int FUSED>
__device__ __forceinline__ void heads_out(const SMem<FUSED>& s, const GP& p,
                                          int rows0, int t, int buf, int tid) {
    const int row = tid >> 2;       // 0..15
    const int sel = tid & 3;
    float sum = 0.0f;
#pragma unroll
    for (int k8 = 0; k8 < 16; k8++) {
        short8 hv = *(const short8*)(&s.h[buf][row][k8 * 8]);
#pragma unroll
        for (int u = 0; u < 8; u++)
            sum += bfraw2f((unsigned short)hv[u]) * s.muw[sel][k8 * 8 + u];
    }
    sum += s.b4[sel];
    const size_t TB2 = (size_t)TT * BN * 2;
    const size_t grow = (size_t)rows0 + row;
    if (sel < 2) p.out[((size_t)t * BN + grow) * 2 + sel] = sum;
    else p.out[TB2 + ((size_t)t * BN + grow) * 2 + (sel - 2)] = __expf(0.5f * sum);
}

template<int FUSED>
__global__ __launch_bounds__(256, 4) void k_gru(GP p) {
    __shared__ __align__(16) SMem<FUSED> s;
    const int tid = threadIdx.x;
    const int lane = tid & 63;
    const int wav = tid >> 6;         // 0..3
    const int wn = wav;               // col quarter
    const int c = lane & 15;
    const int quad = lane >> 4;
    const int rows0 = blockIdx.x * GRU_ROWS;
    const int jb = wn * 32;

    // ---------- P0 (fused only): in-block pre-GEMM (16 rows x 512 cols) ----
    if constexpr (FUSED) {
        floatx4 acc2[8];
#pragma unroll
        for (int j = 0; j < 8; j++) acc2[j] = floatx4{0.f, 0.f, 0.f, 0.f};
        const int nb = wav * 128;
        for (int kc = 0; kc < 33; kc++) {
            const int k = kc * 32 + quad * 8;
            short8 af, bf8[8];
            if (kc < 32) af = ld8f(p.enc + (size_t)(rows0 + c) * MLP + k);
            else         af = ld8f(p.zz + (size_t)(rows0 + c) * ZD + (k - MLP));
#pragma unroll
            for (int j = 0; j < 8; j++) {
                const int n = nb + j * 16 + c;
                bf8[j] = (n < GN) ? ld8f(p.Wih + (size_t)n * WIH_LD + k)
                                  : ld8f(p.Wdec + (size_t)(n - GN) * KD + k);
            }
#pragma unroll
            for (int j = 0; j < 8; j++)
                acc2[j] = __builtin_amdgcn_mfma_f32_16x16x32_bf16(
                    af, bf8[j], acc2[j], 0, 0, 0);
        }
#pragma unroll
        for (int j = 0; j < 8; j++)
#pragma unroll
            for (int r = 0; r < 4; r++)
                s.pre[(quad * 4 + r) * 512 + nb + j * 16 + c] = f2bf(acc2[j][r]);
    }

    // ---------- prologue misc ----------
#pragma unroll
    for (int u = tid; u < 512; u += 256) {
        int sel = u >> 7, k = u & 127;
        s.muw[sel][k] = (sel < 2) ? p.Wmu[sel * 128 + k] : p.Wstd[(sel - 2) * 128 + k];
    }
    if (tid < 4) s.b4[tid] = (tid < 2) ? p.bmu[tid] : p.bstd[tid - 2];
    if (tid < GRU_ROWS) {
        const int row = rows0 + tid;
        for (int pp = 0; pp < 2; pp++) {
            float sum = p.btv[pp];
            for (int f = 0; f < 6; f++)
                sum += p.lst[(size_t)row * 6 + f] * p.Wtv[pp * 6 + f];
            s.a0[tid][pp] = sum;
        }
        float px = p.lpos[(size_t)row * 2];
        float py = p.lpos[(size_t)row * 2 + 1];
        float prevx = 0.f, prevy = 0.f;
        for (int j = 0; j < NSG; j++) {
            float rx = (p.sg[((size_t)row * NSG + j) * 2] - px) * 0.01f;
            float ry = (p.sg[((size_t)row * NSG + j) * 2 + 1] - py) * 0.01f;
            float vx = (rx - prevx) * (1.0f / DTC), vy = (ry - prevy) * (1.0f / DTC);
            prevx = rx; prevy = ry;
            float st4[4] = {rx, ry, vx, vy};
            for (int pp = 0; pp < 2; pp++) {
                float sum = p.bsg[pp];
                for (int f = 0; f < 4; f++) sum += st4[f] * p.Wsg[pp * 4 + f];
                s.sgf[j][tid][pp] = sum;
            }
        }
    }
    int upd[4];
#pragma unroll
    for (int i = 0; i < 4; i++) upd[i] = p.upd[i];

    // W_hh fragments (step-invariant, register-resident; no wm duplicates now)
    short8 Wb[2][3][4];
    short8 Wb4[2][2];
    float Wa2[2][2], Ws2[2][2], bhh2[2];
#pragma unroll
    for (int jt2 = 0; jt2 < 2; jt2++) {
#pragma unroll
        for (int g = 0; g < 3; g++) {
            const int n = g * 128 + jb + jt2 * 16 + c;
#pragma unroll
            for (int kc = 0; kc < 4; kc++)
                Wb[jt2][g][kc] = ld8f(p.Whh + (size_t)n * HD + kc * 32 + quad * 8);
            if (g < 2) {
                short8 v = {0, 0, 0, 0, 0, 0, 0, 0};
                if (quad == 0) {
                    const float* q = p.Wih + (size_t)n * WIH_LD + KD;
                    v[0] = bfbits(q[0]); v[1] = bfbits(q[1]);
                    v[2] = bfbits(q[2]); v[3] = bfbits(q[3]);
                }
                Wb4[jt2][g] = v;
            }
        }
        const int n2 = 256 + jb + jt2 * 16 + c;
        const float* q2 = p.Wih + (size_t)n2 * WIH_LD + KD;
        Wa2[jt2][0] = q2[0]; Wa2[jt2][1] = q2[1];
        Ws2[jt2][0] = q2[2]; Ws2[jt2][1] = q2[3];
        bhh2[jt2] = p.bhh[n2];
    }

    __syncthreads();   // s.pre (if fused) + sgf/a0/muw ready

    // ---------- P1: consume pre-GEMM; h0 -> buf 1; stage all ext ----------
    floatx4 gzx[2][3];
#pragma unroll
    for (int jt2 = 0; jt2 < 2; jt2++) {
#pragma unroll
        for (int g = 0; g < 3; g++) {
            const int n = g * 128 + jb + jt2 * 16 + c;
            float bias = p.bih[n] + ((g < 2) ? p.bhh[n] : 0.0f);
            floatx4 v;
#pragma unroll
            for (int r = 0; r < 4; r++) {
                const int mrow = quad * 4 + r;
                float raw;
                if constexpr (FUSED) raw = bf2f(s.pre[mrow * 512 + n]);
                else raw = bf2f(p.P[(size_t)(rows0 + mrow) * PLD + n]);
                v[r] = raw + bias;
            }
            gzx[jt2][g] = v;
        }
    }
    float hreg[2][4];
#pragma unroll
    for (int jt2 = 0; jt2 < 2; jt2++) {
        const int hcol = jb + jt2 * 16 + c;
        float bd = p.bdec[hcol];
#pragma unroll
        for (int r = 0; r < 4; r++) {
            const int mrow = quad * 4 + r;
            float raw;
            if constexpr (FUSED) raw = bf2f(s.pre[mrow * 512 + GN + hcol]);
            else raw = bf2f(p.P[(size_t)(rows0 + mrow) * PLD + GN + hcol]);
            float hv = raw + bd;
            hreg[jt2][r] = hv;
            s.h[1][mrow][hcol] = f2bf(hv);
        }
    }
    if (tid < TT * GRU_ROWS) {
        const int t = tid >> 4, row = tid & (GRU_ROWS - 1);
        float a0v, a1v;
        if (t == 0) { a0v = s.a0[row][0]; a1v = s.a0[row][1]; }
        else {
            const float* fp = p.fut + ((size_t)(t - 1) * BN + rows0 + row) * 6 + 2;
            a0v = fp[0]; a1v = fp[1];
        }
        int jj = 0;
#pragma unroll
        for (int q = 1; q < NSG; q++) if (upd[q] <= t) jj = q;
        s.ext[t][row][0] = f2bf(a0v);
        s.ext[t][row][1] = f2bf(a1v);
        s.ext[t][row][2] = f2bf(s.sgf[jj][row][0]);
        s.ext[t][row][3] = f2bf(s.sgf[jj][row][1]);
    }
    __syncthreads();

    // ---------- T loop: 1 lgkm-barrier per step ----------
    for (int t = 0; t < TT; t++) {
        const int bi = (t & 1) ^ 1;   // holds h_{t-1}
        const int bo = t & 1;

        floatx4 acc[2][3];
#pragma unroll
        for (int jt2 = 0; jt2 < 2; jt2++) {
            acc[jt2][0] = gzx[jt2][0];
            acc[jt2][1] = gzx[jt2][1];
            floatx4 bb; bb[0] = bb[1] = bb[2] = bb[3] = bhh2[jt2];
            acc[jt2][2] = bb;
        }
#pragma unroll
        for (int kc = 0; kc < 4; kc++) {
            short8 am = *(const short8*)(&s.h[bi][c][kc * 32 + quad * 8]);
#pragma unroll
            for (int jt2 = 0; jt2 < 2; jt2++)
#pragma unroll
                for (int g = 0; g < 3; g++)
                    acc[jt2][g] = __builtin_amdgcn_mfma_f32_16x16x32_bf16(
                        am, Wb[jt2][g][kc], acc[jt2][g], 0, 0, 0);
        }
        {
            short8 am4 = {0, 0, 0, 0, 0, 0, 0, 0};
            if (quad == 0) {
                short4_t e = *(const short4_t*)(&s.ext[t][c][0]);
                am4[0] = e[0]; am4[1] = e[1]; am4[2] = e[2]; am4[3] = e[3];
            }
#pragma unroll
            for (int jt2 = 0; jt2 < 2; jt2++)
#pragma unroll
                for (int g = 0; g < 2; g++)
                    acc[jt2][g] = __builtin_amdgcn_mfma_f32_16x16x32_bf16(
                        am4, Wb4[jt2][g], acc[jt2][g], 0, 0, 0);
        }

        // heads for step t-1 (reads buf bi) overlap with this step's compute
        if (t > 0 && tid < 64) heads_out<FUSED>(s, p, rows0, t - 1, bi, tid);

        // gates + h update -> buf bo
#pragma unroll
        for (int r = 0; r < 4; r++) {
            const int mrow = quad * 4 + r;
            short4_t e4 = *(const short4_t*)(&s.ext[t][mrow][0]);
            float a0v = bfraw2f((unsigned short)e4[0]);
            float a1v = bfraw2f((unsigned short)e4[1]);
            float s0v = bfraw2f((unsigned short)e4[2]);
            float s1v = bfraw2f((unsigned short)e4[3]);
#pragma unroll
            for (int jt2 = 0; jt2 < 2; jt2++) {
                float rr = sigm(acc[jt2][0][r]);
                float zg = sigm(acc[jt2][1][r]);
                float tn = a0v * Wa2[jt2][0] + a1v * Wa2[jt2][1]
                         + s0v * Ws2[jt2][0] + s1v * Ws2[jt2][1];
                float narg = gzx[jt2][2][r] + tn + rr * acc[jt2][2][r];
                float nn = tanh_f(narg);
                float hv = nn + zg * (hreg[jt2][r] - nn);
                hreg[jt2][r] = hv;
                s.h[bo][mrow][jb + jt2 * 16 + c] = f2bf(hv);
            }
        }
        barrier_lgkm();
    }
    if (tid < 64) heads_out<FUSED>(s, p, rows0, TT - 1, (TT - 1) & 1, tid);
}

extern "C" void kernel_launch(void* const* d_in, const int* in_sizes, int n_in,
                              void* d_out, int out_size, void* d_ws, size_t ws_size,
                              hipStream_t stream) {
    GP p;
    p.lst  = (const float*)d_in[0];
    p.lpos = (const float*)d_in[1];
    p.enc  = (const float*)d_in[2];
    p.zz   = (const float*)d_in[3];
    p.sg   = (const float*)d_in[4];
    p.fut  = (const float*)d_in[5];
    p.upd  = (const int*)d_in[6];
    p.Wdec = (const float*)d_in[7];
    p.bdec = (const float*)d_in[8];
    p.Wtv  = (const float*)d_in[9];
    p.btv  = (const float*)d_in[10];
    p.Wih  = (const float*)d_in[11];
    p.bih  = (const float*)d_in[12];
    p.Whh  = (const float*)d_in[13];
    p.bhh  = (const float*)d_in[14];
    p.Wmu  = (const float*)d_in[15];
    p.bmu  = (const float*)d_in[16];
    p.Wstd = (const float*)d_in[17];
    p.bstd = (const float*)d_in[18];
    p.Wsg  = (const float*)d_in[19];
    p.bsg  = (const float*)d_in[20];
    p.out  = (float*)d_out;
    p.P    = nullptr;

    const size_t needP = (size_t)BN * PLD * sizeof(bf16);   // 16.78 MB
    if (ws_size >= needP) {
        bf16* P = (bf16*)d_ws;
        p.P = P;
        k_gemm<<<dim3(128, 4), 512, 0, stream>>>(p.enc, p.zz, p.Wih, p.Wdec, P);
        k_gru<0><<<BN / GRU_ROWS, 256, 0, stream>>>(p);
    } else {
        k_gru<1><<<BN / GRU_ROWS, 256, 0, stream>>>(p);
    }
}

// Round 2
// 265.177 us; speedup vs baseline: 1.7326x; 1.7326x over previous
//
#include <hip/hip_runtime.h>
#include <hip/hip_bf16.h>

#define BN 16384
#define TT 12
#define MLP 1024
#define ZD 32
#define HD 128
#define KD 1056          // MLP+ZD
#define GN 384           // 3*H
#define WIH_LD 1060      // MLP+ZD+2*NPRED
#define NSG 4
#define DTC 1.6f
#define PLD 512          // P leading dim: [gates_zx(384) | h0(128)]
#define SLD 40           // GEMM LDS tile row stride (bf16): 80B -> <=2-way banks
#define GRU_ROWS 16      // rows per k_gru block (256 threads, 4 waves)

typedef __attribute__((ext_vector_type(8))) short short8;
typedef __attribute__((ext_vector_type(4))) short short4_t;
typedef __attribute__((ext_vector_type(4))) float floatx4;
typedef __hip_bfloat16 bf16;

__device__ __forceinline__ float bf2f(bf16 v) { return __bfloat162float(v); }
__device__ __forceinline__ bf16 f2bf(float v) { return __float2bfloat16(v); }
__device__ __forceinline__ short bfbits(float x) {
    bf16 t = __float2bfloat16(x);
    return __builtin_bit_cast(short, t);
}
__device__ __forceinline__ float bfraw2f(unsigned short u) {
    return __uint_as_float(((unsigned int)u) << 16);
}
// rcp-based gates: saves div sequence; |err| ~1ulp of rcp, fine vs 3.4e-2 thr
__device__ __forceinline__ float sigm(float x) {
    return __builtin_amdgcn_rcpf(1.0f + __expf(-x));
}
__device__ __forceinline__ float tanh_f(float x) {
    return 1.0f - 2.0f * __builtin_amdgcn_rcpf(1.0f + __expf(2.0f * x));
}
__device__ __forceinline__ short8 pack8(floatx4 a, floatx4 b) {
    short8 v;
    v[0]=bfbits(a[0]); v[1]=bfbits(a[1]); v[2]=bfbits(a[2]); v[3]=bfbits(a[3]);
    v[4]=bfbits(b[0]); v[5]=bfbits(b[1]); v[6]=bfbits(b[2]); v[7]=bfbits(b[3]);
    return v;
}
__device__ __forceinline__ short8 ld8f(const float* q) {
    return pack8(*(const floatx4*)q, *(const floatx4*)(q + 4));
}
// barrier that waits LDS ops only — leaves global loads/stores in flight
__device__ __forceinline__ void barrier_lgkm() {
    asm volatile("s_waitcnt lgkmcnt(0)\n\ts_barrier" ::: "memory");
}

struct GP {
    const float *lst, *lpos, *enc, *zz, *sg, *fut;
    const int* upd;
    const float *Wdec, *bdec, *Wtv, *btv, *Wih, *bih, *Whh, *bhh;
    const float *Wmu, *bmu, *Wstd, *bstd, *Wsg, *bsg;
    const bf16* P;        // null in fused path
    float* out;
};

// ---------------------------------------------------------------------------
// k_gemm: P[B,512] = zx @ [W_ih[:, :1056] | W_dec_hidden]^T  (raw, no bias)
// Tile 128x128, grid (128,4). Double-buffered LDS, 2-deep register prefetch,
// one lgkm-only barrier per kc (global loads fly across barriers).
// (unchanged — isolate the k_gru launch-bounds fix this round)
// ---------------------------------------------------------------------------
__global__ __launch_bounds__(512, 4) void k_gemm(
    const float* __restrict__ enc, const float* __restrict__ zz,
    const float* __restrict__ Wih, const float* __restrict__ Wdec,
    bf16* __restrict__ P)
{
    __shared__ __align__(16) bf16 sA[2][128 * SLD];
    __shared__ __align__(16) bf16 sB[2][128 * SLD];
    const int tid = threadIdx.x;
    const int lane = tid & 63;
    const int wav = tid >> 6;
    const int wm2 = wav >> 2;         // 0..1
    const int wn2 = wav & 3;          // 0..3
    const int c = lane & 15;
    const int quad = lane >> 4;
    const int m0 = blockIdx.x * 128;
    const int n0 = blockIdx.y * 128;

    const int srow = tid >> 2;        // 0..127
    const int scq = (tid & 3) * 8;    // 0/8/16/24
    const int nn = n0 + srow;
    const float* arow = enc + (size_t)(m0 + srow) * MLP + scq;
    const float* zrow = zz + (size_t)(m0 + srow) * ZD + scq;
    const float* brow = (nn < GN) ? Wih + (size_t)nn * WIH_LD + scq
                                  : Wdec + (size_t)(nn - GN) * KD + scq;

    floatx4 pa[2][2], pb[2][2];
    // preload kc=0 (slot 0) and kc=1 (slot 1)
#pragma unroll
    for (int s0 = 0; s0 < 2; s0++) {
        const float* qa = arow + s0 * 32;
        const float* qb = brow + s0 * 32;
        pa[s0][0] = *(const floatx4*)qa; pa[s0][1] = *(const floatx4*)(qa + 4);
        pb[s0][0] = *(const floatx4*)qb; pb[s0][1] = *(const floatx4*)(qb + 4);
    }

    floatx4 acc[4][2];
#pragma unroll
    for (int i = 0; i < 4; i++)
#pragma unroll
        for (int j = 0; j < 2; j++) acc[i][j] = floatx4{0.f, 0.f, 0.f, 0.f};

    for (int kc = 0; kc < 33; kc++) {
        const int sl = kc & 1;
        *(short8*)&sA[sl][srow * SLD + scq] = pack8(pa[sl][0], pa[sl][1]);
        *(short8*)&sB[sl][srow * SLD + scq] = pack8(pb[sl][0], pb[sl][1]);
        if (kc + 2 < 33) {
            const int k2 = (kc + 2) * 32;
            const float* qa = (kc + 2 < 32) ? arow + k2 : zrow;
            const float* qb = brow + k2;
            pa[sl][0] = *(const floatx4*)qa; pa[sl][1] = *(const floatx4*)(qa + 4);
            pb[sl][0] = *(const floatx4*)qb; pb[sl][1] = *(const floatx4*)(qb + 4);
        }
        barrier_lgkm();
        short8 a[4], b[2];
#pragma unroll
        for (int i = 0; i < 4; i++)
            a[i] = *(const short8*)&sA[sl][(wm2 * 64 + i * 16 + c) * SLD + quad * 8];
#pragma unroll
        for (int j = 0; j < 2; j++)
            b[j] = *(const short8*)&sB[sl][(wn2 * 32 + j * 16 + c) * SLD + quad * 8];
#pragma unroll
        for (int i = 0; i < 4; i++)
#pragma unroll
            for (int j = 0; j < 2; j++)
                acc[i][j] = __builtin_amdgcn_mfma_f32_16x16x32_bf16(
                    a[i], b[j], acc[i][j], 0, 0, 0);
        // no trailing barrier: next iter writes the other LDS slot; all waves'
        // slot-sl reads are lgkm-complete before anyone passes the next barrier
    }
#pragma unroll
    for (int i = 0; i < 4; i++)
#pragma unroll
        for (int j = 0; j < 2; j++)
#pragma unroll
            for (int r = 0; r < 4; r++)
                P[(size_t)(m0 + wm2 * 64 + i * 16 + quad * 4 + r) * PLD
                  + n0 + wn2 * 32 + j * 16 + c] = f2bf(acc[i][j][r]);
}

// ---------------------------------------------------------------------------
// GRU kernel. FUSED=1: in-block pre-GEMM (ws too small). FUSED=0: read P.
// 256 threads / 16 rows / 1024 blocks. Per-wave register layout needs ~128
// VGPR (Wb=96 + gzx/hreg/acc). __launch_bounds__ 2nd arg MUST be <=2:
// (256,4) capped VGPR at 64 -> spilled Whh fragments -> 930 MB of scratch
// traffic refilled every T step (round-1: FETCH 652 MB, 279 us). (256,2)
// lets the allocator land at ~128 VGPR; runtime occupancy 4 waves/SIMD.
// ---------------------------------------------------------------------------
template<int FUSED> struct SMem {
    static constexpr int PRE_N = FUSED ? GRU_ROWS * 512 : 16;
    bf16 pre[PRE_N];
    bf16 h[2][GRU_ROWS][136];   // 272B rows: 2-way banks (free) for b128 reads
    bf16 ext[TT][GRU_ROWS][4];  // per-step (a0,a1,sg0,sg1)
    float sgf[NSG][GRU_ROWS][2];
    float a0[GRU_ROWS][2];
    float muw[4][132];          // +4 pad: kills 4-way same-bank head reads
    float b4[4];
};

template<int FUSED>
__device__ __forceinline__ void heads_out(const SMem<FUSED>& s, const GP& p,
                                          int rows0, int t, int buf, int tid) {
    const int row = tid >> 2;       // 0..15
    const int sel = tid & 3;
    float sum = 0.0f;
#pragma unroll
    for (int k8 = 0; k8 < 16; k8++) {
        short8 hv = *(const short8*)(&s.h[buf][row][k8 * 8]);
#pragma unroll
        for (int u = 0; u < 8; u++)
            sum += bfraw2f((unsigned short)hv[u]) * s.muw[sel][k8 * 8 + u];
    }
    sum += s.b4[sel];
    const size_t TB2 = (size_t)TT * BN * 2;
    const size_t grow = (size_t)rows0 + row;
    if (sel < 2) p.out[((size_t)t * BN + grow) * 2 + sel] = sum;
    else p.out[TB2 + ((size_t)t * BN + grow) * 2 + (sel - 2)] = __expf(0.5f * sum);
}

template<int FUSED>
__global__ __launch_bounds__(256, 2) void k_gru(GP p) {
    __shared__ __align__(16) SMem<FUSED> s;
    const int tid = threadIdx.x;
    const int lane = tid & 63;
    const int wav = tid >> 6;         // 0..3
    const int wn = wav;               // col quarter
    const int c = lane & 15;
    const int quad = lane >> 4;
    const int rows0 = blockIdx.x * GRU_ROWS;
    const int jb = wn * 32;

    // ---------- P0 (fused only): in-block pre-GEMM (16 rows x 512 cols) ----
    if constexpr (FUSED) {
        floatx4 acc2[8];
#pragma unroll
        for (int j = 0; j < 8; j++) acc2[j] = floatx4{0.f, 0.f, 0.f, 0.f};
        const int nb = wav * 128;
        for (int kc = 0; kc < 33; kc++) {
            const int k = kc * 32 + quad * 8;
            short8 af, bf8[8];
            if (kc < 32) af = ld8f(p.enc + (size_t)(rows0 + c) * MLP + k);
            else         af = ld8f(p.zz + (size_t)(rows0 + c) * ZD + (k - MLP));
#pragma unroll
            for (int j = 0; j < 8; j++) {
                const int n = nb + j * 16 + c;
                bf8[j] = (n < GN) ? ld8f(p.Wih + (size_t)n * WIH_LD + k)
                                  : ld8f(p.Wdec + (size_t)(n - GN) * KD + k);
            }
#pragma unroll
            for (int j = 0; j < 8; j++)
                acc2[j] = __builtin_amdgcn_mfma_f32_16x16x32_bf16(
                    af, bf8[j], acc2[j], 0, 0, 0);
        }
#pragma unroll
        for (int j = 0; j < 8; j++)
#pragma unroll
            for (int r = 0; r < 4; r++)
                s.pre[(quad * 4 + r) * 512 + nb + j * 16 + c] = f2bf(acc2[j][r]);
    }

    // ---------- prologue misc ----------
#pragma unroll
    for (int u = tid; u < 512; u += 256) {
        int sel = u >> 7, k = u & 127;
        s.muw[sel][k] = (sel < 2) ? p.Wmu[sel * 128 + k] : p.Wstd[(sel - 2) * 128 + k];
    }
    if (tid < 4) s.b4[tid] = (tid < 2) ? p.bmu[tid] : p.bstd[tid - 2];
    if (tid < GRU_ROWS) {
        const int row = rows0 + tid;
        for (int pp = 0; pp < 2; pp++) {
            float sum = p.btv[pp];
            for (int f = 0; f < 6; f++)
                sum += p.lst[(size_t)row * 6 + f] * p.Wtv[pp * 6 + f];
            s.a0[tid][pp] = sum;
        }
        float px = p.lpos[(size_t)row * 2];
        float py = p.lpos[(size_t)row * 2 + 1];
        float prevx = 0.f, prevy = 0.f;
        for (int j = 0; j < NSG; j++) {
            float rx = (p.sg[((size_t)row * NSG + j) * 2] - px) * 0.01f;
            float ry = (p.sg[((size_t)row * NSG + j) * 2 + 1] - py) * 0.01f;
            float vx = (rx - prevx) * (1.0f / DTC), vy = (ry - prevy) * (1.0f / DTC);
            prevx = rx; prevy = ry;
            float st4[4] = {rx, ry, vx, vy};
            for (int pp = 0; pp < 2; pp++) {
                float sum = p.bsg[pp];
                for (int f = 0; f < 4; f++) sum += st4[f] * p.Wsg[pp * 4 + f];
                s.sgf[j][tid][pp] = sum;
            }
        }
    }
    int upd[4];
#pragma unroll
    for (int i = 0; i < 4; i++) upd[i] = p.upd[i];

    // W_hh fragments (step-invariant, register-resident; ~96 VGPR)
    short8 Wb[2][3][4];
    short8 Wb4[2][2];
    float Wa2[2][2], Ws2[2][2], bhh2[2];
#pragma unroll
    for (int jt2 = 0; jt2 < 2; jt2++) {
#pragma unroll
        for (int g = 0; g < 3; g++) {
            const int n = g * 128 + jb + jt2 * 16 + c;
#pragma unroll
            for (int kc = 0; kc < 4; kc++)
                Wb[jt2][g][kc] = ld8f(p.Whh + (size_t)n * HD + kc * 32 + quad * 8);
            if (g < 2) {
                short8 v = {0, 0, 0, 0, 0, 0, 0, 0};
                if (quad == 0) {
                    const float* q = p.Wih + (size_t)n * WIH_LD + KD;
                    v[0] = bfbits(q[0]); v[1] = bfbits(q[1]);
                    v[2] = bfbits(q[2]); v[3] = bfbits(q[3]);
                }
                Wb4[jt2][g] = v;
            }
        }
        const int n2 = 256 + jb + jt2 * 16 + c;
        const float* q2 = p.Wih + (size_t)n2 * WIH_LD + KD;
        Wa2[jt2][0] = q2[0]; Wa2[jt2][1] = q2[1];
        Ws2[jt2][0] = q2[2]; Ws2[jt2][1] = q2[3];
        bhh2[jt2] = p.bhh[n2];
    }

    __syncthreads();   // s.pre (if fused) + sgf/a0/muw ready

    // ---------- P1: consume pre-GEMM; h0 -> buf 1; stage all ext ----------
    floatx4 gzx[2][3];
#pragma unroll
    for (int jt2 = 0; jt2 < 2; jt2++) {
#pragma unroll
        for (int g = 0; g < 3; g++) {
            const int n = g * 128 + jb + jt2 * 16 + c;
            float bias = p.bih[n] + ((g < 2) ? p.bhh[n] : 0.0f);
            floatx4 v;
#pragma unroll
            for (int r = 0; r < 4; r++) {
                const int mrow = quad * 4 + r;
                float raw;
                if constexpr (FUSED) raw = bf2f(s.pre[mrow * 512 + n]);
                else raw = bf2f(p.P[(size_t)(rows0 + mrow) * PLD + n]);
                v[r] = raw + bias;
            }
            gzx[jt2][g] = v;
        }
    }
    float hreg[2][4];
#pragma unroll
    for (int jt2 = 0; jt2 < 2; jt2++) {
        const int hcol = jb + jt2 * 16 + c;
        float bd = p.bdec[hcol];
#pragma unroll
        for (int r = 0; r < 4; r++) {
            const int mrow = quad * 4 + r;
            float raw;
            if constexpr (FUSED) raw = bf2f(s.pre[mrow * 512 + GN + hcol]);
            else raw = bf2f(p.P[(size_t)(rows0 + mrow) * PLD + GN + hcol]);
            float hv = raw + bd;
            hreg[jt2][r] = hv;
            s.h[1][mrow][hcol] = f2bf(hv);
        }
    }
    if (tid < TT * GRU_ROWS) {
        const int t = tid >> 4, row = tid & (GRU_ROWS - 1);
        float a0v, a1v;
        if (t == 0) { a0v = s.a0[row][0]; a1v = s.a0[row][1]; }
        else {
            const float* fp = p.fut + ((size_t)(t - 1) * BN + rows0 + row) * 6 + 2;
            a0v = fp[0]; a1v = fp[1];
        }
        int jj = 0;
#pragma unroll
        for (int q = 1; q < NSG; q++) if (upd[q] <= t) jj = q;
        s.ext[t][row][0] = f2bf(a0v);
        s.ext[t][row][1] = f2bf(a1v);
        s.ext[t][row][2] = f2bf(s.sgf[jj][row][0]);
        s.ext[t][row][3] = f2bf(s.sgf[jj][row][1]);
    }
    __syncthreads();

    // ---------- T loop: 1 lgkm-barrier per step ----------
    for (int t = 0; t < TT; t++) {
        const int bi = (t & 1) ^ 1;   // holds h_{t-1}
        const int bo = t & 1;

        floatx4 acc[2][3];
#pragma unroll
        for (int jt2 = 0; jt2 < 2; jt2++) {
            acc[jt2][0] = gzx[jt2][0];
            acc[jt2][1] = gzx[jt2][1];
            floatx4 bb; bb[0] = bb[1] = bb[2] = bb[3] = bhh2[jt2];
            acc[jt2][2] = bb;
        }
#pragma unroll
        for (int kc = 0; kc < 4; kc++) {
            short8 am = *(const short8*)(&s.h[bi][c][kc * 32 + quad * 8]);
#pragma unroll
            for (int jt2 = 0; jt2 < 2; jt2++)
#pragma unroll
                for (int g = 0; g < 3; g++)
                    acc[jt2][g] = __builtin_amdgcn_mfma_f32_16x16x32_bf16(
                        am, Wb[jt2][g][kc], acc[jt2][g], 0, 0, 0);
        }
        {
            short8 am4 = {0, 0, 0, 0, 0, 0, 0, 0};
            if (quad == 0) {
                short4_t e = *(const short4_t*)(&s.ext[t][c][0]);
                am4[0] = e[0]; am4[1] = e[1]; am4[2] = e[2]; am4[3] = e[3];
            }
#pragma unroll
            for (int jt2 = 0; jt2 < 2; jt2++)
#pragma unroll
                for (int g = 0; g < 2; g++)
                    acc[jt2][g] = __builtin_amdgcn_mfma_f32_16x16x32_bf16(
                        am4, Wb4[jt2][g], acc[jt2][g], 0, 0, 0);
        }

        // heads for step t-1 (reads buf bi) overlap with this step's compute
        if (t > 0 && tid < 64) heads_out<FUSED>(s, p, rows0, t - 1, bi, tid);

        // gates + h update -> buf bo
#pragma unroll
        for (int r = 0; r < 4; r++) {
            const int mrow = quad * 4 + r;
            short4_t e4 = *(const short4_t*)(&s.ext[t][mrow][0]);
            float a0v = bfraw2f((unsigned short)e4[0]);
            float a1v = bfraw2f((unsigned short)e4[1]);
            float s0v = bfraw2f((unsigned short)e4[2]);
            float s1v = bfraw2f((unsigned short)e4[3]);
#pragma unroll
            for (int jt2 = 0; jt2 < 2; jt2++) {
                float rr = sigm(acc[jt2][0][r]);
                float zg = sigm(acc[jt2][1][r]);
                float tn = a0v * Wa2[jt2][0] + a1v * Wa2[jt2][1]
                         + s0v * Ws2[jt2][0] + s1v * Ws2[jt2][1];
                float narg = gzx[jt2][2][r] + tn + rr * acc[jt2][2][r];
                float nn = tanh_f(narg);
                float hv = nn + zg * (hreg[jt2][r] - nn);
                hreg[jt2][r] = hv;
                s.h[bo][mrow][jb + jt2 * 16 + c] = f2bf(hv);
            }
        }
        barrier_lgkm();
    }
    if (tid < 64) heads_out<FUSED>(s, p, rows0, TT - 1, (TT - 1) & 1, tid);
}

extern "C" void kernel_launch(void* const* d_in, const int* in_sizes, int n_in,
                              void* d_out, int out_size, void* d_ws, size_t ws_size,
                              hipStream_t stream) {
    GP p;
    p.lst  = (const float*)d_in[0];
    p.lpos = (const float*)d_in[1];
    p.enc  = (const float*)d_in[2];
    p.zz   = (const float*)d_in[3];
    p.sg   = (const float*)d_in[4];
    p.fut  = (const float*)d_in[5];
    p.upd  = (const int*)d_in[6];
    p.Wdec = (const float*)d_in[7];
    p.bdec = (const float*)d_in[8];
    p.Wtv  = (const float*)d_in[9];
    p.btv  = (const float*)d_in[10];
    p.Wih  = (const float*)d_in[11];
    p.bih  = (const float*)d_in[12];
    p.Whh  = (const float*)d_in[13];
    p.bhh  = (const float*)d_in[14];
    p.Wmu  = (const float*)d_in[15];
    p.bmu  = (const float*)d_in[16];
    p.Wstd = (const float*)d_in[17];
    p.bstd = (const float*)d_in[18];
    p.Wsg  = (const float*)d_in[19];
    p.bsg  = (const float*)d_in[20];
    p.out  = (float*)d_out;
    p.P    = nullptr;

    const size_t needP = (size_t)BN * PLD * sizeof(bf16);   // 16.78 MB
    if (ws_size >= needP) {
        bf16* P = (bf16*)d_ws;
        p.P = P;
        k_gemm<<<dim3(128, 4), 512, 0, stream>>>(p.enc, p.zz, p.Wih, p.Wdec, P);
        k_gru<0><<<BN / GRU_ROWS, 256, 0, stream>>>(p);
    } else {
        k_gru<1><<<BN / GRU_ROWS, 256, 0, stream>>>(p);
    }
}